// Round 1
// baseline (7141.008 us; speedup 1.0000x reference)
//
#include <hip/hip_runtime.h>
#include <hip/hip_bf16.h>

#define N_    64
#define CIN   128
#define COUT  256
#define T_    128
#define V_    25
#define TOUT  64
#define VOUT  13
#define EPS_  1e-5f

#define CI_CHUNK 32
#define LROWS    9   // t_in rows staged per block: [8*tg-1, 8*tg+7]

typedef __hip_bfloat16 bf16;

__device__ __forceinline__ float ldv(const bf16* p)  { return __bfloat162float(*p); }
__device__ __forceinline__ float ldv(const float* p) { return *p; }
__device__ __forceinline__ void  stv(bf16* p, float v)  { *p = __float2bfloat16(v); }
__device__ __forceinline__ void  stv(float* p, float v) { *p = v; }

// vectorized 4-element load -> 4 floats
__device__ __forceinline__ void load4(const float* p, float& a, float& b, float& c, float& d) {
    float4 v = *reinterpret_cast<const float4*>(p);
    a = v.x; b = v.y; c = v.z; d = v.w;
}
__device__ __forceinline__ void load4(const bf16* p, float& a, float& b, float& c, float& d) {
    ushort4 u = *reinterpret_cast<const ushort4*>(p);
    a = __uint_as_float((unsigned)u.x << 16);
    b = __uint_as_float((unsigned)u.y << 16);
    c = __uint_as_float((unsigned)u.z << 16);
    d = __uint_as_float((unsigned)u.w << 16);
}

// Reduce (s, ss) across a 256-thread block; valid in thread 0 afterwards.
__device__ __forceinline__ void blockReduce2(float& s, float& ss) {
    __shared__ float ls[4], lss[4];
    int lane = threadIdx.x & 63, wid = threadIdx.x >> 6;
#pragma unroll
    for (int o = 32; o > 0; o >>= 1) {
        s  += __shfl_down(s, o, 64);
        ss += __shfl_down(ss, o, 64);
    }
    if (lane == 0) { ls[wid] = s; lss[wid] = ss; }
    __syncthreads();
    if (threadIdx.x == 0) {
        s  = ls[0] + ls[1] + ls[2] + ls[3];
        ss = lss[0] + lss[1] + lss[2] + lss[3];
    }
}

// ---- dtype detector + zero-init of bn1 partial sums ----
__global__ void detect_k(const unsigned short* __restrict__ xr, int* flag,
                         float* __restrict__ s1, float* __restrict__ q1) {
    if (threadIdx.x < CIN) { s1[threadIdx.x] = 0.f; q1[threadIdx.x] = 0.f; }
    __shared__ int cnt;
    if (threadIdx.x == 0) cnt = 0;
    __syncthreads();
    int c = 0;
    for (int i = threadIdx.x; i < 8192; i += 256) {
        int e = (xr[i] >> 7) & 0xFF;
        if (e >= 192) c++;
    }
    atomicAdd(&cnt, c);
    __syncthreads();
    if (threadIdx.x == 0) flag[0] = (cnt > 0) ? 1 : 0;
}

// ---- BN1 partial sums: grid (CIN, 4), vectorized loads, atomic accumulate ----
template<int MODE, typename DT>
__global__ __launch_bounds__(256) void bn1_k(const int* __restrict__ flag,
                                             const DT* __restrict__ x,
                                             float* __restrict__ s1, float* __restrict__ q1) {
    if (flag[0] != MODE) return;
    const int c  = blockIdx.x;
    const int n0 = blockIdx.y * (N_ / 4);
    float s = 0.f, ss = 0.f;
    // T_*V_ = 3200 = 800 groups of 4
    for (int idx = threadIdx.x; idx < (N_ / 4) * 800; idx += 256) {
        int n = n0 + idx / 800;
        int q = idx - (idx / 800) * 800;
        const DT* xp = x + ((size_t)n * CIN + c) * (T_ * V_) + q * 4;
        float v0, v1, v2, v3;
        load4(xp, v0, v1, v2, v3);
        s  += (v0 + v1) + (v2 + v3);
        ss += (v0 * v0 + v1 * v1) + (v2 * v2 + v3 * v3);
    }
    blockReduce2(s, ss);
    if (threadIdx.x == 0) { atomicAdd(&s1[c], s); atomicAdd(&q1[c], ss); }
}

// ---- BN1 finalize: a1,b1 from partial sums ----
template<int MODE, typename DT>
__global__ void bn1fin_k(const int* __restrict__ flag,
                         const DT* __restrict__ gamma, const DT* __restrict__ beta,
                         const float* __restrict__ s1, const float* __restrict__ q1,
                         float* __restrict__ a1, float* __restrict__ b1) {
    if (flag[0] != MODE) return;
    int c = threadIdx.x;  // 128 threads
    float cnt = (float)(N_ * T_ * V_);
    float mean = s1[c] / cnt;
    float var = q1[c] / cnt - mean * mean;
    float a = ldv(&gamma[c]) * rsqrtf(var + EPS_);
    a1[c] = a;
    b1[c] = ldv(&beta[c]) - mean * a;
}

// ---- fused shift_in + BN1 + conv3x3 s2 p1 + bias + relu -> y ----
// block: (tg = group of 4 'to', n). 256 thr = 4 waves (one to each) x 64 cgroups.
// thread computes 4 co x 13 vo. LDS: 32-ci chunk x 9 t-rows x 28 v (16B-aligned rows).
template<int MODE, typename DT>
__global__ __launch_bounds__(256, 3) void conv_k(const int* __restrict__ flag,
                                                 const DT* __restrict__ x,
                                                 const DT* __restrict__ wgt,
                                                 const DT* __restrict__ bias,
                                                 const DT* __restrict__ s_in,
                                                 const float* __restrict__ a1,
                                                 const float* __restrict__ b1,
                                                 DT* __restrict__ y) {
    if (flag[0] != MODE) return;
    __shared__ __align__(16) float sh[CI_CHUNK][LROWS][28];
    const int tg  = blockIdx.x;         // 0..15
    const int n   = blockIdx.y;
    const int tid = threadIdx.x;
    const int ts  = tid >> 6;           // wave id -> to offset (wave-uniform)
    const int cg  = tid & 63;
    const int co0 = cg * 4;
    const int to  = tg * 4 + ts;
    const int tbase = 8 * tg - 1;       // t_in = tbase + lt, lt in [0,9)

    float acc[4][VOUT];
#pragma unroll
    for (int m = 0; m < 4; m++)
#pragma unroll
        for (int vo = 0; vo < VOUT; vo++) acc[m][vo] = 0.f;

#pragma unroll 1
    for (int cc = 0; cc < CIN; cc += CI_CHUNK) {
        // ---- stage shift_in+BN1 chunk into LDS ----
        for (int e = tid; e < CI_CHUNK * LROWS * 27; e += 256) {
            int ci = e / (LROWS * 27);
            int r0 = e - ci * (LROWS * 27);
            int lt = r0 / 27;
            int vv = r0 - lt * 27;
            int t_in = tbase + lt;
            int v_in = vv - 1;
            float hv = 0.f;
            if (t_in >= 0 && t_in < T_ && v_in >= 0 && v_in < V_) {
                int gci = cc + ci;
                float s = ldv(&s_in[gci]);
                float tsrc = (float)t_in + s;
                float f0 = floorf(tsrc);
                float frac = tsrc - f0;
                int i0 = (int)f0;
                int i1 = i0 + 1;
                float w0 = (i0 >= 0 && i0 < T_) ? (1.f - frac) : 0.f;
                float w1 = (i1 >= 0 && i1 < T_) ? frac : 0.f;
                int i0c = min(max(i0, 0), T_ - 1);
                int i1c = min(max(i1, 0), T_ - 1);
                const DT* xc = x + ((size_t)n * CIN + gci) * (T_ * V_);
                float xv = w0 * ldv(&xc[i0c * V_ + v_in]) + w1 * ldv(&xc[i1c * V_ + v_in]);
                hv = a1[gci] * xv + b1[gci] * (w0 + w1);
            }
            sh[ci][lt][vv] = hv;
        }
        __syncthreads();

        // ---- register-blocked inner product over this ci chunk ----
#pragma unroll 1
        for (int ci = 0; ci < CI_CHUNK; ci++) {
            const DT* wb = wgt + ((size_t)co0 * CIN + (cc + ci)) * 9;
            float w[4][9];
#pragma unroll
            for (int m = 0; m < 4; m++) {
                const DT* wm = wb + (size_t)m * CIN * 9;
#pragma unroll
                for (int k = 0; k < 9; k++) w[m][k] = ldv(&wm[k]);
            }
#pragma unroll
            for (int kt = 0; kt < 3; kt++) {
                // wave-uniform row -> broadcast ds_read_b128, conflict-free
                const float4* rp = reinterpret_cast<const float4*>(&sh[ci][2 * ts + kt][0]);
                float r[28];
#pragma unroll
                for (int q = 0; q < 7; q++) {
                    float4 t4 = rp[q];
                    r[4 * q + 0] = t4.x; r[4 * q + 1] = t4.y;
                    r[4 * q + 2] = t4.z; r[4 * q + 3] = t4.w;
                }
#pragma unroll
                for (int m = 0; m < 4; m++)
#pragma unroll
                    for (int vo = 0; vo < VOUT; vo++)
                        acc[m][vo] += w[m][3 * kt + 0] * r[2 * vo + 0]
                                    + w[m][3 * kt + 1] * r[2 * vo + 1]
                                    + w[m][3 * kt + 2] * r[2 * vo + 2];
            }
        }
        __syncthreads();
    }

    // ---- epilogue: bias + relu + store ----
#pragma unroll
    for (int m = 0; m < 4; m++) {
        int co = co0 + m;
        float bi = ldv(&bias[co]);
        DT* yp = y + (((size_t)n * COUT + co) * TOUT + to) * VOUT;
#pragma unroll
        for (int vo = 0; vo < VOUT; vo++) stv(&yp[vo], fmaxf(acc[m][vo] + bi, 0.f));
    }
}

// ---- BN2 stats over z = shift_out(y): one block per output channel ----
template<int MODE, typename DT>
__global__ void bn2_k(const int* __restrict__ flag, const DT* __restrict__ y,
                      const DT* __restrict__ s_out,
                      const DT* __restrict__ gamma, const DT* __restrict__ beta,
                      float* __restrict__ a2, float* __restrict__ b2) {
    if (flag[0] != MODE) return;
    int co = blockIdx.x;
    float sv = ldv(&s_out[co]);
    float s = 0.f, ss = 0.f;
    for (int i = threadIdx.x; i < N_ * TOUT * VOUT; i += 256) {
        int n = i / (TOUT * VOUT);
        int r = i % (TOUT * VOUT);
        int to = r / VOUT;
        int vo = r % VOUT;
        float tsrc = (float)to + sv;
        float f0 = floorf(tsrc);
        float frac = tsrc - f0;
        int i0 = (int)f0, i1 = i0 + 1;
        float w0 = (i0 >= 0 && i0 < TOUT) ? (1.f - frac) : 0.f;
        float w1 = (i1 >= 0 && i1 < TOUT) ? frac : 0.f;
        int i0c = min(max(i0, 0), TOUT - 1);
        int i1c = min(max(i1, 0), TOUT - 1);
        const DT* yc = y + ((size_t)n * COUT + co) * (TOUT * VOUT);
        float z = w0 * ldv(&yc[i0c * VOUT + vo]) + w1 * ldv(&yc[i1c * VOUT + vo]);
        s += z; ss += z * z;
    }
    blockReduce2(s, ss);
    if (threadIdx.x == 0) {
        float cnt = (float)(N_ * TOUT * VOUT);
        float mean = s / cnt;
        float var = ss / cnt - mean * mean;
        float a = ldv(&gamma[co]) * rsqrtf(var + EPS_);
        a2[co] = a;
        b2[co] = ldv(&beta[co]) - mean * a;
    }
}

// ---- in-place: out = a2 * shift_out(y) + b2, per (n,co) plane via LDS ----
template<int MODE, typename DT>
__global__ void final_k(const int* __restrict__ flag, DT* __restrict__ y,
                        const DT* __restrict__ s_out,
                        const float* __restrict__ a2, const float* __restrict__ b2) {
    if (flag[0] != MODE) return;
    __shared__ float pl[TOUT * VOUT];
    int co = blockIdx.x, n = blockIdx.y;
    DT* base = y + ((size_t)n * COUT + co) * (TOUT * VOUT);
    for (int i = threadIdx.x; i < TOUT * VOUT; i += 256) pl[i] = ldv(&base[i]);
    __syncthreads();
    float sv = ldv(&s_out[co]);
    float A = a2[co], B = b2[co];
    for (int i = threadIdx.x; i < TOUT * VOUT; i += 256) {
        int to = i / VOUT, vo = i % VOUT;
        float tsrc = (float)to + sv;
        float f0 = floorf(tsrc);
        float frac = tsrc - f0;
        int i0 = (int)f0, i1 = i0 + 1;
        float w0 = (i0 >= 0 && i0 < TOUT) ? (1.f - frac) : 0.f;
        float w1 = (i1 >= 0 && i1 < TOUT) ? frac : 0.f;
        int i0c = min(max(i0, 0), TOUT - 1);
        int i1c = min(max(i1, 0), TOUT - 1);
        float z = w0 * pl[i0c * VOUT + vo] + w1 * pl[i1c * VOUT + vo];
        stv(&base[i], A * z + B);
    }
}

extern "C" void kernel_launch(void* const* d_in, const int* in_sizes, int n_in,
                              void* d_out, int out_size, void* d_ws, size_t ws_size,
                              hipStream_t stream) {
    // ws: flag (256B) | a1[128] | b1[128] | a2[256] | b2[256] | s1[128] | q1[128]
    int*   flag = (int*)d_ws;
    float* a1 = (float*)((char*)d_ws + 256);
    float* b1 = a1 + 128;
    float* a2 = b1 + 128;
    float* b2 = a2 + 256;
    float* s1 = b2 + 256;
    float* q1 = s1 + 128;

    detect_k<<<1, 256, 0, stream>>>((const unsigned short*)d_in[0], flag, s1, q1);

    // MODE 0: bf16 tensors
    const bf16* xb    = (const bf16*)d_in[0];
    const bf16* g1b   = (const bf16*)d_in[1];
    const bf16* be1b  = (const bf16*)d_in[2];
    const bf16* sinb  = (const bf16*)d_in[3];
    const bf16* wbb   = (const bf16*)d_in[4];
    const bf16* cbb   = (const bf16*)d_in[5];
    const bf16* soutb = (const bf16*)d_in[6];
    const bf16* g2b   = (const bf16*)d_in[7];
    const bf16* be2b  = (const bf16*)d_in[8];
    bf16* yb = (bf16*)d_out;
    // MODE 1: fp32 tensors
    const float* xf    = (const float*)d_in[0];
    const float* g1f   = (const float*)d_in[1];
    const float* be1f  = (const float*)d_in[2];
    const float* sinf_ = (const float*)d_in[3];
    const float* wbf   = (const float*)d_in[4];
    const float* cbf   = (const float*)d_in[5];
    const float* soutf = (const float*)d_in[6];
    const float* g2f   = (const float*)d_in[7];
    const float* be2f  = (const float*)d_in[8];
    float* yf = (float*)d_out;

    bn1_k<0, bf16> <<<dim3(CIN, 4), 256, 0, stream>>>(flag, xb, s1, q1);
    bn1_k<1, float><<<dim3(CIN, 4), 256, 0, stream>>>(flag, xf, s1, q1);
    bn1fin_k<0, bf16> <<<1, 128, 0, stream>>>(flag, g1b, be1b, s1, q1, a1, b1);
    bn1fin_k<1, float><<<1, 128, 0, stream>>>(flag, g1f, be1f, s1, q1, a1, b1);

    conv_k<0, bf16> <<<dim3(TOUT / 4, N_), 256, 0, stream>>>(flag, xb, wbb, cbb, sinb, a1, b1, yb);
    conv_k<1, float><<<dim3(TOUT / 4, N_), 256, 0, stream>>>(flag, xf, wbf, cbf, sinf_, a1, b1, yf);

    bn2_k<0, bf16> <<<dim3(COUT), 256, 0, stream>>>(flag, yb, soutb, g2b, be2b, a2, b2);
    bn2_k<1, float><<<dim3(COUT), 256, 0, stream>>>(flag, yf, soutf, g2f, be2f, a2, b2);

    final_k<0, bf16> <<<dim3(COUT, N_), 256, 0, stream>>>(flag, yb, soutb, a2, b2);
    final_k<1, float><<<dim3(COUT, N_), 256, 0, stream>>>(flag, yf, soutf, a2, b2);
}

// Round 2
// 1703.786 us; speedup vs baseline: 4.1913x; 4.1913x over previous
//
#include <hip/hip_runtime.h>
#include <hip/hip_bf16.h>

#define N_    64
#define CIN   128
#define COUT  256
#define T_    128
#define V_    25
#define TOUT  64
#define VOUT  13
#define EPS_  1e-5f

#define CI_CHUNK 32
#define LROWS    5   // t_in rows staged per block: [4*tg-1, 4*tg+3]

typedef __hip_bfloat16 bf16;

__device__ __forceinline__ float ldv(const bf16* p)  { return __bfloat162float(*p); }
__device__ __forceinline__ float ldv(const float* p) { return *p; }
__device__ __forceinline__ void  stv(bf16* p, float v)  { *p = __float2bfloat16(v); }
__device__ __forceinline__ void  stv(float* p, float v) { *p = v; }

// vectorized 4-element load -> 4 floats
__device__ __forceinline__ void load4(const float* p, float& a, float& b, float& c, float& d) {
    float4 v = *reinterpret_cast<const float4*>(p);
    a = v.x; b = v.y; c = v.z; d = v.w;
}
__device__ __forceinline__ void load4(const bf16* p, float& a, float& b, float& c, float& d) {
    ushort4 u = *reinterpret_cast<const ushort4*>(p);
    a = __uint_as_float((unsigned)u.x << 16);
    b = __uint_as_float((unsigned)u.y << 16);
    c = __uint_as_float((unsigned)u.z << 16);
    d = __uint_as_float((unsigned)u.w << 16);
}

// Reduce (s, ss) across a 256-thread block; valid in thread 0 afterwards.
__device__ __forceinline__ void blockReduce2(float& s, float& ss) {
    __shared__ float ls[4], lss[4];
    int lane = threadIdx.x & 63, wid = threadIdx.x >> 6;
#pragma unroll
    for (int o = 32; o > 0; o >>= 1) {
        s  += __shfl_down(s, o, 64);
        ss += __shfl_down(ss, o, 64);
    }
    if (lane == 0) { ls[wid] = s; lss[wid] = ss; }
    __syncthreads();
    if (threadIdx.x == 0) {
        s  = ls[0] + ls[1] + ls[2] + ls[3];
        ss = lss[0] + lss[1] + lss[2] + lss[3];
    }
}

// ---- dtype detector + zero-init of bn1 partial sums ----
__global__ void detect_k(const unsigned short* __restrict__ xr, int* flag,
                         float* __restrict__ s1, float* __restrict__ q1) {
    if (threadIdx.x < CIN) { s1[threadIdx.x] = 0.f; q1[threadIdx.x] = 0.f; }
    __shared__ int cnt;
    if (threadIdx.x == 0) cnt = 0;
    __syncthreads();
    int c = 0;
    for (int i = threadIdx.x; i < 8192; i += 256) {
        int e = (xr[i] >> 7) & 0xFF;
        if (e >= 192) c++;
    }
    atomicAdd(&cnt, c);
    __syncthreads();
    if (threadIdx.x == 0) flag[0] = (cnt > 0) ? 1 : 0;
}

// ---- BN1 partial sums: grid (CIN, 4), vectorized loads, atomic accumulate ----
template<int MODE, typename DT>
__global__ __launch_bounds__(256) void bn1_k(const int* __restrict__ flag,
                                             const DT* __restrict__ x,
                                             float* __restrict__ s1, float* __restrict__ q1) {
    if (flag[0] != MODE) return;
    const int c  = blockIdx.x;
    const int n0 = blockIdx.y * (N_ / 4);
    float s = 0.f, ss = 0.f;
    // T_*V_ = 3200 = 800 groups of 4
    for (int idx = threadIdx.x; idx < (N_ / 4) * 800; idx += 256) {
        int n = n0 + idx / 800;
        int q = idx - (idx / 800) * 800;
        const DT* xp = x + ((size_t)n * CIN + c) * (T_ * V_) + q * 4;
        float v0, v1, v2, v3;
        load4(xp, v0, v1, v2, v3);
        s  += (v0 + v1) + (v2 + v3);
        ss += (v0 * v0 + v1 * v1) + (v2 * v2 + v3 * v3);
    }
    blockReduce2(s, ss);
    if (threadIdx.x == 0) { atomicAdd(&s1[c], s); atomicAdd(&q1[c], ss); }
}

// ---- BN1 finalize: a1,b1 from partial sums ----
template<int MODE, typename DT>
__global__ void bn1fin_k(const int* __restrict__ flag,
                         const DT* __restrict__ gamma, const DT* __restrict__ beta,
                         const float* __restrict__ s1, const float* __restrict__ q1,
                         float* __restrict__ a1, float* __restrict__ b1) {
    if (flag[0] != MODE) return;
    int c = threadIdx.x;  // 128 threads
    float cnt = (float)(N_ * T_ * V_);
    float mean = s1[c] / cnt;
    float var = q1[c] / cnt - mean * mean;
    float a = ldv(&gamma[c]) * rsqrtf(var + EPS_);
    a1[c] = a;
    b1[c] = ldv(&beta[c]) - mean * a;
}

// ---- fused shift_in + BN1 + conv3x3 s2 p1 + bias + relu -> y ----
// block: (tg = pair of 'to', n). 256 thr: ts = tid>>7 (wave-uniform to-offset),
// cg = tid&127 -> co0 = 2*cg. Thread computes 2 co x 13 vo (acc=26 regs).
// LDS: 32-ci chunk x 5 t-rows x 28 v (16B-aligned rows), 17.5 KB.
template<int MODE, typename DT>
__global__ __launch_bounds__(256) void conv_k(const int* __restrict__ flag,
                                              const DT* __restrict__ x,
                                              const DT* __restrict__ wgt,
                                              const DT* __restrict__ bias,
                                              const DT* __restrict__ s_in,
                                              const float* __restrict__ a1,
                                              const float* __restrict__ b1,
                                              DT* __restrict__ y) {
    if (flag[0] != MODE) return;
    __shared__ __align__(16) float sh[CI_CHUNK][LROWS][28];
    const int tg  = blockIdx.x;         // 0..31
    const int n   = blockIdx.y;
    const int tid = threadIdx.x;
    const int ts  = tid >> 7;           // 0/1, wave-uniform -> to offset
    const int cg  = tid & 127;
    const int co0 = cg * 2;
    const int to  = tg * 2 + ts;
    const int tbase = 4 * tg - 1;       // t_in = tbase + lt, lt in [0,5)

    float acc[2][VOUT];
#pragma unroll
    for (int m = 0; m < 2; m++)
#pragma unroll
        for (int vo = 0; vo < VOUT; vo++) acc[m][vo] = 0.f;

#pragma unroll 1
    for (int cc = 0; cc < CIN; cc += CI_CHUNK) {
        // ---- stage shift_in+BN1 chunk into LDS ----
        for (int e = tid; e < CI_CHUNK * LROWS * 27; e += 256) {
            int ci = e / (LROWS * 27);
            int r0 = e - ci * (LROWS * 27);
            int lt = r0 / 27;
            int vv = r0 - lt * 27;
            int t_in = tbase + lt;
            int v_in = vv - 1;
            float hv = 0.f;
            if (t_in >= 0 && t_in < T_ && v_in >= 0 && v_in < V_) {
                int gci = cc + ci;
                float s = ldv(&s_in[gci]);
                float tsrc = (float)t_in + s;
                float f0 = floorf(tsrc);
                float frac = tsrc - f0;
                int i0 = (int)f0;
                int i1 = i0 + 1;
                float w0 = (i0 >= 0 && i0 < T_) ? (1.f - frac) : 0.f;
                float w1 = (i1 >= 0 && i1 < T_) ? frac : 0.f;
                int i0c = min(max(i0, 0), T_ - 1);
                int i1c = min(max(i1, 0), T_ - 1);
                const DT* xc = x + ((size_t)n * CIN + gci) * (T_ * V_);
                float xv = w0 * ldv(&xc[i0c * V_ + v_in]) + w1 * ldv(&xc[i1c * V_ + v_in]);
                hv = a1[gci] * xv + b1[gci] * (w0 + w1);
            }
            sh[ci][lt][vv] = hv;
        }
        __syncthreads();

        // ---- register-blocked inner product over this ci chunk ----
#pragma unroll 1
        for (int ci = 0; ci < CI_CHUNK; ci++) {
            const DT* wb = wgt + ((size_t)co0 * CIN + (cc + ci)) * 9;
            float w[2][9];
#pragma unroll
            for (int m = 0; m < 2; m++) {
                const DT* wm = wb + (size_t)m * CIN * 9;
#pragma unroll
                for (int k = 0; k < 9; k++) w[m][k] = ldv(&wm[k]);
            }
#pragma unroll
            for (int kt = 0; kt < 3; kt++) {
                // wave-uniform row -> broadcast ds_read_b128, conflict-free
                const float4* rp = reinterpret_cast<const float4*>(&sh[ci][2 * ts + kt][0]);
                float r[28];
#pragma unroll
                for (int q = 0; q < 7; q++) {
                    float4 t4 = rp[q];
                    r[4 * q + 0] = t4.x; r[4 * q + 1] = t4.y;
                    r[4 * q + 2] = t4.z; r[4 * q + 3] = t4.w;
                }
#pragma unroll
                for (int m = 0; m < 2; m++)
#pragma unroll
                    for (int vo = 0; vo < VOUT; vo++)
                        acc[m][vo] += w[m][3 * kt + 0] * r[2 * vo + 0]
                                    + w[m][3 * kt + 1] * r[2 * vo + 1]
                                    + w[m][3 * kt + 2] * r[2 * vo + 2];
            }
        }
        __syncthreads();
    }

    // ---- epilogue: bias + relu + store ----
#pragma unroll
    for (int m = 0; m < 2; m++) {
        int co = co0 + m;
        float bi = ldv(&bias[co]);
        DT* yp = y + (((size_t)n * COUT + co) * TOUT + to) * VOUT;
#pragma unroll
        for (int vo = 0; vo < VOUT; vo++) stv(&yp[vo], fmaxf(acc[m][vo] + bi, 0.f));
    }
}

// ---- BN2 stats over z = shift_out(y): one block per output channel ----
template<int MODE, typename DT>
__global__ void bn2_k(const int* __restrict__ flag, const DT* __restrict__ y,
                      const DT* __restrict__ s_out,
                      const DT* __restrict__ gamma, const DT* __restrict__ beta,
                      float* __restrict__ a2, float* __restrict__ b2) {
    if (flag[0] != MODE) return;
    int co = blockIdx.x;
    float sv = ldv(&s_out[co]);
    float s = 0.f, ss = 0.f;
    for (int i = threadIdx.x; i < N_ * TOUT * VOUT; i += 256) {
        int n = i / (TOUT * VOUT);
        int r = i % (TOUT * VOUT);
        int to = r / VOUT;
        int vo = r % VOUT;
        float tsrc = (float)to + sv;
        float f0 = floorf(tsrc);
        float frac = tsrc - f0;
        int i0 = (int)f0, i1 = i0 + 1;
        float w0 = (i0 >= 0 && i0 < TOUT) ? (1.f - frac) : 0.f;
        float w1 = (i1 >= 0 && i1 < TOUT) ? frac : 0.f;
        int i0c = min(max(i0, 0), TOUT - 1);
        int i1c = min(max(i1, 0), TOUT - 1);
        const DT* yc = y + ((size_t)n * COUT + co) * (TOUT * VOUT);
        float z = w0 * ldv(&yc[i0c * VOUT + vo]) + w1 * ldv(&yc[i1c * VOUT + vo]);
        s += z; ss += z * z;
    }
    blockReduce2(s, ss);
    if (threadIdx.x == 0) {
        float cnt = (float)(N_ * TOUT * VOUT);
        float mean = s / cnt;
        float var = ss / cnt - mean * mean;
        float a = ldv(&gamma[co]) * rsqrtf(var + EPS_);
        a2[co] = a;
        b2[co] = ldv(&beta[co]) - mean * a;
    }
}

// ---- in-place: out = a2 * shift_out(y) + b2, per (n,co) plane via LDS ----
template<int MODE, typename DT>
__global__ void final_k(const int* __restrict__ flag, DT* __restrict__ y,
                        const DT* __restrict__ s_out,
                        const float* __restrict__ a2, const float* __restrict__ b2) {
    if (flag[0] != MODE) return;
    __shared__ float pl[TOUT * VOUT];
    int co = blockIdx.x, n = blockIdx.y;
    DT* base = y + ((size_t)n * COUT + co) * (TOUT * VOUT);
    for (int i = threadIdx.x; i < TOUT * VOUT; i += 256) pl[i] = ldv(&base[i]);
    __syncthreads();
    float sv = ldv(&s_out[co]);
    float A = a2[co], B = b2[co];
    for (int i = threadIdx.x; i < TOUT * VOUT; i += 256) {
        int to = i / VOUT, vo = i % VOUT;
        float tsrc = (float)to + sv;
        float f0 = floorf(tsrc);
        float frac = tsrc - f0;
        int i0 = (int)f0, i1 = i0 + 1;
        float w0 = (i0 >= 0 && i0 < TOUT) ? (1.f - frac) : 0.f;
        float w1 = (i1 >= 0 && i1 < TOUT) ? frac : 0.f;
        int i0c = min(max(i0, 0), TOUT - 1);
        int i1c = min(max(i1, 0), TOUT - 1);
        float z = w0 * pl[i0c * VOUT + vo] + w1 * pl[i1c * VOUT + vo];
        stv(&base[i], A * z + B);
    }
}

extern "C" void kernel_launch(void* const* d_in, const int* in_sizes, int n_in,
                              void* d_out, int out_size, void* d_ws, size_t ws_size,
                              hipStream_t stream) {
    // ws: flag (256B) | a1[128] | b1[128] | a2[256] | b2[256] | s1[128] | q1[128]
    int*   flag = (int*)d_ws;
    float* a1 = (float*)((char*)d_ws + 256);
    float* b1 = a1 + 128;
    float* a2 = b1 + 128;
    float* b2 = a2 + 256;
    float* s1 = b2 + 256;
    float* q1 = s1 + 128;

    detect_k<<<1, 256, 0, stream>>>((const unsigned short*)d_in[0], flag, s1, q1);

    // MODE 0: bf16 tensors
    const bf16* xb    = (const bf16*)d_in[0];
    const bf16* g1b   = (const bf16*)d_in[1];
    const bf16* be1b  = (const bf16*)d_in[2];
    const bf16* sinb  = (const bf16*)d_in[3];
    const bf16* wbb   = (const bf16*)d_in[4];
    const bf16* cbb   = (const bf16*)d_in[5];
    const bf16* soutb = (const bf16*)d_in[6];
    const bf16* g2b   = (const bf16*)d_in[7];
    const bf16* be2b  = (const bf16*)d_in[8];
    bf16* yb = (bf16*)d_out;
    // MODE 1: fp32 tensors
    const float* xf    = (const float*)d_in[0];
    const float* g1f   = (const float*)d_in[1];
    const float* be1f  = (const float*)d_in[2];
    const float* sinf_ = (const float*)d_in[3];
    const float* wbf   = (const float*)d_in[4];
    const float* cbf   = (const float*)d_in[5];
    const float* soutf = (const float*)d_in[6];
    const float* g2f   = (const float*)d_in[7];
    const float* be2f  = (const float*)d_in[8];
    float* yf = (float*)d_out;

    bn1_k<0, bf16> <<<dim3(CIN, 4), 256, 0, stream>>>(flag, xb, s1, q1);
    bn1_k<1, float><<<dim3(CIN, 4), 256, 0, stream>>>(flag, xf, s1, q1);
    bn1fin_k<0, bf16> <<<1, 128, 0, stream>>>(flag, g1b, be1b, s1, q1, a1, b1);
    bn1fin_k<1, float><<<1, 128, 0, stream>>>(flag, g1f, be1f, s1, q1, a1, b1);

    conv_k<0, bf16> <<<dim3(TOUT / 2, N_), 256, 0, stream>>>(flag, xb, wbb, cbb, sinb, a1, b1, yb);
    conv_k<1, float><<<dim3(TOUT / 2, N_), 256, 0, stream>>>(flag, xf, wbf, cbf, sinf_, a1, b1, yf);

    bn2_k<0, bf16> <<<dim3(COUT), 256, 0, stream>>>(flag, yb, soutb, g2b, be2b, a2, b2);
    bn2_k<1, float><<<dim3(COUT), 256, 0, stream>>>(flag, yf, soutf, g2f, be2f, a2, b2);

    final_k<0, bf16> <<<dim3(COUT, N_), 256, 0, stream>>>(flag, yb, soutb, a2, b2);
    final_k<1, float><<<dim3(COUT, N_), 256, 0, stream>>>(flag, yf, soutf, a2, b2);
}

// Round 3
// 1285.685 us; speedup vs baseline: 5.5542x; 1.3252x over previous
//
#include <hip/hip_runtime.h>
#include <hip/hip_bf16.h>

#define N_    64
#define CIN   128
#define COUT  256
#define T_    128
#define V_    25
#define TOUT  64
#define VOUT  13
#define EPS_  1e-5f

#define CI_CHUNK 16
#define LROWS    9   // t_in rows staged per block: [8*tg-1, 8*tg+7]

typedef __hip_bfloat16 bf16;

__device__ __forceinline__ float ldv(const bf16* p)  { return __bfloat162float(*p); }
__device__ __forceinline__ float ldv(const float* p) { return *p; }
__device__ __forceinline__ void  stv(bf16* p, float v)  { *p = __float2bfloat16(v); }
__device__ __forceinline__ void  stv(float* p, float v) { *p = v; }

// vectorized 4-element load -> 4 floats
__device__ __forceinline__ void load4(const float* p, float& a, float& b, float& c, float& d) {
    float4 v = *reinterpret_cast<const float4*>(p);
    a = v.x; b = v.y; c = v.z; d = v.w;
}
__device__ __forceinline__ void load4(const bf16* p, float& a, float& b, float& c, float& d) {
    ushort4 u = *reinterpret_cast<const ushort4*>(p);
    a = __uint_as_float((unsigned)u.x << 16);
    b = __uint_as_float((unsigned)u.y << 16);
    c = __uint_as_float((unsigned)u.z << 16);
    d = __uint_as_float((unsigned)u.w << 16);
}

// Reduce (s, ss) across a 256-thread block; valid in thread 0 afterwards.
__device__ __forceinline__ void blockReduce2(float& s, float& ss) {
    __shared__ float ls[4], lss[4];
    int lane = threadIdx.x & 63, wid = threadIdx.x >> 6;
#pragma unroll
    for (int o = 32; o > 0; o >>= 1) {
        s  += __shfl_down(s, o, 64);
        ss += __shfl_down(ss, o, 64);
    }
    if (lane == 0) { ls[wid] = s; lss[wid] = ss; }
    __syncthreads();
    if (threadIdx.x == 0) {
        s  = ls[0] + ls[1] + ls[2] + ls[3];
        ss = lss[0] + lss[1] + lss[2] + lss[3];
    }
}

// ---- dtype detector + zero-init of bn1 partial sums ----
__global__ void detect_k(const unsigned short* __restrict__ xr, int* flag,
                         float* __restrict__ s1, float* __restrict__ q1) {
    if (threadIdx.x < CIN) { s1[threadIdx.x] = 0.f; q1[threadIdx.x] = 0.f; }
    __shared__ int cnt;
    if (threadIdx.x == 0) cnt = 0;
    __syncthreads();
    int c = 0;
    for (int i = threadIdx.x; i < 8192; i += 256) {
        int e = (xr[i] >> 7) & 0xFF;
        if (e >= 192) c++;
    }
    atomicAdd(&cnt, c);
    __syncthreads();
    if (threadIdx.x == 0) flag[0] = (cnt > 0) ? 1 : 0;
}

// ---- BN1 partial sums: grid (CIN, 4), vectorized loads, atomic accumulate ----
template<int MODE, typename DT>
__global__ __launch_bounds__(256) void bn1_k(const int* __restrict__ flag,
                                             const DT* __restrict__ x,
                                             float* __restrict__ s1, float* __restrict__ q1) {
    if (flag[0] != MODE) return;
    const int c  = blockIdx.x;
    const int n0 = blockIdx.y * (N_ / 4);
    float s = 0.f, ss = 0.f;
    // T_*V_ = 3200 = 800 groups of 4
    for (int idx = threadIdx.x; idx < (N_ / 4) * 800; idx += 256) {
        int n = n0 + idx / 800;
        int q = idx - (idx / 800) * 800;
        const DT* xp = x + ((size_t)n * CIN + c) * (T_ * V_) + q * 4;
        float v0, v1, v2, v3;
        load4(xp, v0, v1, v2, v3);
        s  += (v0 + v1) + (v2 + v3);
        ss += (v0 * v0 + v1 * v1) + (v2 * v2 + v3 * v3);
    }
    blockReduce2(s, ss);
    if (threadIdx.x == 0) { atomicAdd(&s1[c], s); atomicAdd(&q1[c], ss); }
}

// ---- BN1 finalize: a1,b1 from partial sums ----
template<int MODE, typename DT>
__global__ void bn1fin_k(const int* __restrict__ flag,
                         const DT* __restrict__ gamma, const DT* __restrict__ beta,
                         const float* __restrict__ s1, const float* __restrict__ q1,
                         float* __restrict__ a1, float* __restrict__ b1) {
    if (flag[0] != MODE) return;
    int c = threadIdx.x;  // 128 threads
    float cnt = (float)(N_ * T_ * V_);
    float mean = s1[c] / cnt;
    float var = q1[c] / cnt - mean * mean;
    float a = ldv(&gamma[c]) * rsqrtf(var + EPS_);
    a1[c] = a;
    b1[c] = ldv(&beta[c]) - mean * a;
}

// ---- fused shift_in + BN1 + conv3x3 s2 p1 + bias + relu -> y ----
// Wave-uniform weights: each wave owns 16 consecutive co (base forced to SGPR
// via readfirstlane -> scalar/broadcast weight loads, no 64-line gathers).
// Lanes = spatial: tq = lane>>4 (4 'to' per block), vo = lane&15 (13 valid).
// Per ci: 6 ds_read_b64 input taps (bank-balanced) reused across 16 co,
// 144 FMA. acc = 16 VGPRs. LDS: 16ci x 9 t-rows x 28 v = 16.1 KB.
template<int MODE, typename DT>
__global__ __launch_bounds__(256) void conv_k(const int* __restrict__ flag,
                                              const DT* __restrict__ x,
                                              const DT* __restrict__ wgt,
                                              const DT* __restrict__ bias,
                                              const DT* __restrict__ s_in,
                                              const float* __restrict__ a1,
                                              const float* __restrict__ b1,
                                              DT* __restrict__ y) {
    if (flag[0] != MODE) return;
    __shared__ __align__(16) float sh[CI_CHUNK][LROWS][28];
    const int tg   = blockIdx.x;        // 0..15 : group of 4 'to'
    const int cog  = blockIdx.y;        // 0..3  : group of 64 co
    const int n    = blockIdx.z;        // 0..63
    const int tid  = threadIdx.x;
    const int wid  = tid >> 6;
    const int lane = tid & 63;
    const int tq   = lane >> 4;         // 0..3
    const int vo   = lane & 15;         // 0..15 (13 valid)
    const int voc  = min(vo, 12);       // clamp -> idle lanes broadcast lane-12 addr
    const int co_w = __builtin_amdgcn_readfirstlane(cog * 64 + wid * 16);
    const int to   = tg * 4 + tq;
    const int tbase = 8 * tg - 1;       // t_in = tbase + lt, lt in [0,9)

    float acc[16];
#pragma unroll
    for (int j = 0; j < 16; j++) acc[j] = 0.f;

#pragma unroll 1
    for (int cc = 0; cc < CIN; cc += CI_CHUNK) {
        // ---- stage shift_in+BN1 chunk into LDS ----
        for (int e = tid; e < CI_CHUNK * LROWS * 27; e += 256) {
            int ci = e / (LROWS * 27);
            int r0 = e - ci * (LROWS * 27);
            int lt = r0 / 27;
            int vv = r0 - lt * 27;
            int t_in = tbase + lt;
            int v_in = vv - 1;
            float hv = 0.f;
            if (t_in >= 0 && t_in < T_ && v_in >= 0 && v_in < V_) {
                int gci = cc + ci;
                float s = ldv(&s_in[gci]);
                float tsrc = (float)t_in + s;
                float f0 = floorf(tsrc);
                float frac = tsrc - f0;
                int i0 = (int)f0;
                int i1 = i0 + 1;
                float w0 = (i0 >= 0 && i0 < T_) ? (1.f - frac) : 0.f;
                float w1 = (i1 >= 0 && i1 < T_) ? frac : 0.f;
                int i0c = min(max(i0, 0), T_ - 1);
                int i1c = min(max(i1, 0), T_ - 1);
                const DT* xc = x + ((size_t)n * CIN + gci) * (T_ * V_);
                float xv = w0 * ldv(&xc[i0c * V_ + v_in]) + w1 * ldv(&xc[i1c * V_ + v_in]);
                hv = a1[gci] * xv + b1[gci] * (w0 + w1);
            }
            sh[ci][lt][vv] = hv;
        }
        __syncthreads();

        // ---- inner product: lanes=spatial, wave=16 co, weights scalar ----
#pragma unroll 1
        for (int ci = 0; ci < CI_CHUNK; ci++) {
            // input taps: per kt one float pair-pair [2vo .. 2vo+3]
            float xv[3][3];
#pragma unroll
            for (int kt = 0; kt < 3; kt++) {
                const float2* rp = reinterpret_cast<const float2*>(&sh[ci][2 * tq + kt][2 * voc]);
                float2 p0 = rp[0];
                float2 p1 = rp[1];
                xv[kt][0] = p0.x; xv[kt][1] = p0.y; xv[kt][2] = p1.x;
            }
            const DT* wrow = wgt + ((size_t)co_w * CIN + (cc + ci)) * 9;
#pragma unroll
            for (int j = 0; j < 16; j++) {
                const DT* wj = wrow + (size_t)j * CIN * 9;
                float a = acc[j];
#pragma unroll
                for (int kt = 0; kt < 3; kt++) {
                    a += ldv(&wj[3 * kt + 0]) * xv[kt][0];
                    a += ldv(&wj[3 * kt + 1]) * xv[kt][1];
                    a += ldv(&wj[3 * kt + 2]) * xv[kt][2];
                }
                acc[j] = a;
            }
        }
        __syncthreads();
    }

    // ---- epilogue: bias + relu + store (valid vo lanes only) ----
    if (vo < VOUT) {
#pragma unroll
        for (int j = 0; j < 16; j++) {
            int co = co_w + j;
            float bi = ldv(&bias[co]);
            DT* yp = y + (((size_t)n * COUT + co) * TOUT + to) * VOUT;
            stv(&yp[vo], fmaxf(acc[j] + bi, 0.f));
        }
    }
}

// ---- BN2 stats over z = shift_out(y): one block per output channel ----
template<int MODE, typename DT>
__global__ void bn2_k(const int* __restrict__ flag, const DT* __restrict__ y,
                      const DT* __restrict__ s_out,
                      const DT* __restrict__ gamma, const DT* __restrict__ beta,
                      float* __restrict__ a2, float* __restrict__ b2) {
    if (flag[0] != MODE) return;
    int co = blockIdx.x;
    float sv = ldv(&s_out[co]);
    float s = 0.f, ss = 0.f;
    for (int i = threadIdx.x; i < N_ * TOUT * VOUT; i += 256) {
        int n = i / (TOUT * VOUT);
        int r = i % (TOUT * VOUT);
        int to = r / VOUT;
        int vo = r % VOUT;
        float tsrc = (float)to + sv;
        float f0 = floorf(tsrc);
        float frac = tsrc - f0;
        int i0 = (int)f0, i1 = i0 + 1;
        float w0 = (i0 >= 0 && i0 < TOUT) ? (1.f - frac) : 0.f;
        float w1 = (i1 >= 0 && i1 < TOUT) ? frac : 0.f;
        int i0c = min(max(i0, 0), TOUT - 1);
        int i1c = min(max(i1, 0), TOUT - 1);
        const DT* yc = y + ((size_t)n * COUT + co) * (TOUT * VOUT);
        float z = w0 * ldv(&yc[i0c * VOUT + vo]) + w1 * ldv(&yc[i1c * VOUT + vo]);
        s += z; ss += z * z;
    }
    blockReduce2(s, ss);
    if (threadIdx.x == 0) {
        float cnt = (float)(N_ * TOUT * VOUT);
        float mean = s / cnt;
        float var = ss / cnt - mean * mean;
        float a = ldv(&gamma[co]) * rsqrtf(var + EPS_);
        a2[co] = a;
        b2[co] = ldv(&beta[co]) - mean * a;
    }
}

// ---- in-place: out = a2 * shift_out(y) + b2, per (n,co) plane via LDS ----
template<int MODE, typename DT>
__global__ void final_k(const int* __restrict__ flag, DT* __restrict__ y,
                        const DT* __restrict__ s_out,
                        const float* __restrict__ a2, const float* __restrict__ b2) {
    if (flag[0] != MODE) return;
    __shared__ float pl[TOUT * VOUT];
    int co = blockIdx.x, n = blockIdx.y;
    DT* base = y + ((size_t)n * COUT + co) * (TOUT * VOUT);
    for (int i = threadIdx.x; i < TOUT * VOUT; i += 256) pl[i] = ldv(&base[i]);
    __syncthreads();
    float sv = ldv(&s_out[co]);
    float A = a2[co], B = b2[co];
    for (int i = threadIdx.x; i < TOUT * VOUT; i += 256) {
        int to = i / VOUT, vo = i % VOUT;
        float tsrc = (float)to + sv;
        float f0 = floorf(tsrc);
        float frac = tsrc - f0;
        int i0 = (int)f0, i1 = i0 + 1;
        float w0 = (i0 >= 0 && i0 < TOUT) ? (1.f - frac) : 0.f;
        float w1 = (i1 >= 0 && i1 < TOUT) ? frac : 0.f;
        int i0c = min(max(i0, 0), TOUT - 1);
        int i1c = min(max(i1, 0), TOUT - 1);
        float z = w0 * pl[i0c * VOUT + vo] + w1 * pl[i1c * VOUT + vo];
        stv(&base[i], A * z + B);
    }
}

extern "C" void kernel_launch(void* const* d_in, const int* in_sizes, int n_in,
                              void* d_out, int out_size, void* d_ws, size_t ws_size,
                              hipStream_t stream) {
    // ws: flag (256B) | a1[128] | b1[128] | a2[256] | b2[256] | s1[128] | q1[128]
    int*   flag = (int*)d_ws;
    float* a1 = (float*)((char*)d_ws + 256);
    float* b1 = a1 + 128;
    float* a2 = b1 + 128;
    float* b2 = a2 + 256;
    float* s1 = b2 + 256;
    float* q1 = s1 + 128;

    detect_k<<<1, 256, 0, stream>>>((const unsigned short*)d_in[0], flag, s1, q1);

    // MODE 0: bf16 tensors
    const bf16* xb    = (const bf16*)d_in[0];
    const bf16* g1b   = (const bf16*)d_in[1];
    const bf16* be1b  = (const bf16*)d_in[2];
    const bf16* sinb  = (const bf16*)d_in[3];
    const bf16* wbb   = (const bf16*)d_in[4];
    const bf16* cbb   = (const bf16*)d_in[5];
    const bf16* soutb = (const bf16*)d_in[6];
    const bf16* g2b   = (const bf16*)d_in[7];
    const bf16* be2b  = (const bf16*)d_in[8];
    bf16* yb = (bf16*)d_out;
    // MODE 1: fp32 tensors
    const float* xf    = (const float*)d_in[0];
    const float* g1f   = (const float*)d_in[1];
    const float* be1f  = (const float*)d_in[2];
    const float* sinf_ = (const float*)d_in[3];
    const float* wbf   = (const float*)d_in[4];
    const float* cbf   = (const float*)d_in[5];
    const float* soutf = (const float*)d_in[6];
    const float* g2f   = (const float*)d_in[7];
    const float* be2f  = (const float*)d_in[8];
    float* yf = (float*)d_out;

    bn1_k<0, bf16> <<<dim3(CIN, 4), 256, 0, stream>>>(flag, xb, s1, q1);
    bn1_k<1, float><<<dim3(CIN, 4), 256, 0, stream>>>(flag, xf, s1, q1);
    bn1fin_k<0, bf16> <<<1, 128, 0, stream>>>(flag, g1b, be1b, s1, q1, a1, b1);
    bn1fin_k<1, float><<<1, 128, 0, stream>>>(flag, g1f, be1f, s1, q1, a1, b1);

    conv_k<0, bf16> <<<dim3(TOUT / 4, COUT / 64, N_), 256, 0, stream>>>(flag, xb, wbb, cbb, sinb, a1, b1, yb);
    conv_k<1, float><<<dim3(TOUT / 4, COUT / 64, N_), 256, 0, stream>>>(flag, xf, wbf, cbf, sinf_, a1, b1, yf);

    bn2_k<0, bf16> <<<dim3(COUT), 256, 0, stream>>>(flag, yb, soutb, g2b, be2b, a2, b2);
    bn2_k<1, float><<<dim3(COUT), 256, 0, stream>>>(flag, yf, soutf, g2f, be2f, a2, b2);

    final_k<0, bf16> <<<dim3(COUT, N_), 256, 0, stream>>>(flag, yb, soutb, a2, b2);
    final_k<1, float><<<dim3(COUT, N_), 256, 0, stream>>>(flag, yf, soutf, a2, b2);
}

// Round 4
// 1048.277 us; speedup vs baseline: 6.8121x; 1.2265x over previous
//
#include <hip/hip_runtime.h>
#include <hip/hip_bf16.h>

#define N_    64
#define CIN   128
#define COUT  256
#define T_    128
#define V_    25
#define TOUT  64
#define VOUT  13
#define EPS_  1e-5f

#define CI_CHUNK 16
#define LROWS    9   // t_in rows staged per block: [8*tg-1, 8*tg+7]

typedef __hip_bfloat16 bf16;

__device__ __forceinline__ float ldv(const bf16* p)  { return __bfloat162float(*p); }
__device__ __forceinline__ float ldv(const float* p) { return *p; }
__device__ __forceinline__ void  stv(bf16* p, float v)  { *p = __float2bfloat16(v); }
__device__ __forceinline__ void  stv(float* p, float v) { *p = v; }

// vectorized 4-element load -> 4 floats
__device__ __forceinline__ void load4(const float* p, float& a, float& b, float& c, float& d) {
    float4 v = *reinterpret_cast<const float4*>(p);
    a = v.x; b = v.y; c = v.z; d = v.w;
}
__device__ __forceinline__ void load4(const bf16* p, float& a, float& b, float& c, float& d) {
    ushort4 u = *reinterpret_cast<const ushort4*>(p);
    a = __uint_as_float((unsigned)u.x << 16);
    b = __uint_as_float((unsigned)u.y << 16);
    c = __uint_as_float((unsigned)u.z << 16);
    d = __uint_as_float((unsigned)u.w << 16);
}

// Reduce (s, ss) across a 256-thread block; valid in thread 0 afterwards.
__device__ __forceinline__ void blockReduce2(float& s, float& ss) {
    __shared__ float ls[4], lss[4];
    int lane = threadIdx.x & 63, wid = threadIdx.x >> 6;
#pragma unroll
    for (int o = 32; o > 0; o >>= 1) {
        s  += __shfl_down(s, o, 64);
        ss += __shfl_down(ss, o, 64);
    }
    if (lane == 0) { ls[wid] = s; lss[wid] = ss; }
    __syncthreads();
    if (threadIdx.x == 0) {
        s  = ls[0] + ls[1] + ls[2] + ls[3];
        ss = lss[0] + lss[1] + lss[2] + lss[3];
    }
}

// ---- dtype detector + zero-init of bn1 partial sums ----
__global__ void detect_k(const unsigned short* __restrict__ xr, int* flag,
                         float* __restrict__ s1, float* __restrict__ q1) {
    if (threadIdx.x < CIN) { s1[threadIdx.x] = 0.f; q1[threadIdx.x] = 0.f; }
    __shared__ int cnt;
    if (threadIdx.x == 0) cnt = 0;
    __syncthreads();
    int c = 0;
    for (int i = threadIdx.x; i < 8192; i += 256) {
        int e = (xr[i] >> 7) & 0xFF;
        if (e >= 192) c++;
    }
    atomicAdd(&cnt, c);
    __syncthreads();
    if (threadIdx.x == 0) flag[0] = (cnt > 0) ? 1 : 0;
}

// ---- weight prepass: convert to fp32, layout [ci][co][9] ----
template<int MODE, typename DT>
__global__ __launch_bounds__(256) void wcvt_k(const int* __restrict__ flag,
                                              const DT* __restrict__ wgt,
                                              float* __restrict__ w32) {
    if (flag[0] != MODE) return;
    int total = COUT * CIN * 9;
    for (int i = blockIdx.x * 256 + threadIdx.x; i < total; i += gridDim.x * 256) {
        int co = i / (CIN * 9);
        int r  = i - co * (CIN * 9);
        int ci = r / 9;
        int k  = r - ci * 9;
        w32[((size_t)ci * COUT + co) * 9 + k] = ldv(&wgt[i]);
    }
}

// ---- BN1 partial sums: grid (CIN, 4), vectorized loads, atomic accumulate ----
template<int MODE, typename DT>
__global__ __launch_bounds__(256) void bn1_k(const int* __restrict__ flag,
                                             const DT* __restrict__ x,
                                             float* __restrict__ s1, float* __restrict__ q1) {
    if (flag[0] != MODE) return;
    const int c  = blockIdx.x;
    const int n0 = blockIdx.y * (N_ / 4);
    float s = 0.f, ss = 0.f;
    // T_*V_ = 3200 = 800 groups of 4
    for (int idx = threadIdx.x; idx < (N_ / 4) * 800; idx += 256) {
        int n = n0 + idx / 800;
        int q = idx - (idx / 800) * 800;
        const DT* xp = x + ((size_t)n * CIN + c) * (T_ * V_) + q * 4;
        float v0, v1, v2, v3;
        load4(xp, v0, v1, v2, v3);
        s  += (v0 + v1) + (v2 + v3);
        ss += (v0 * v0 + v1 * v1) + (v2 * v2 + v3 * v3);
    }
    blockReduce2(s, ss);
    if (threadIdx.x == 0) { atomicAdd(&s1[c], s); atomicAdd(&q1[c], ss); }
}

// ---- BN1 finalize: a1,b1 from partial sums ----
template<int MODE, typename DT>
__global__ void bn1fin_k(const int* __restrict__ flag,
                         const DT* __restrict__ gamma, const DT* __restrict__ beta,
                         const float* __restrict__ s1, const float* __restrict__ q1,
                         float* __restrict__ a1, float* __restrict__ b1) {
    if (flag[0] != MODE) return;
    int c = threadIdx.x;  // 128 threads
    float cnt = (float)(N_ * T_ * V_);
    float mean = s1[c] / cnt;
    float var = q1[c] / cnt - mean * mean;
    float a = ldv(&gamma[c]) * rsqrtf(var + EPS_);
    a1[c] = a;
    b1[c] = ldv(&beta[c]) - mean * a;
}

// ---- fused shift_in + BN1 + conv3x3 s2 p1 + bias + relu -> y ----
// Wave-uniform weights from fp32 [ci][co][9] workspace: per (ci, wave) the
// 16 co x 9 = 144 weights are CONTIGUOUS at a uniform __restrict__ address
// -> compiler scalarizes to s_load_dwordx8/16 (SMEM pipe), inner loop is
// 144 pure v_fmac_f32 acc, s_w, v_x per ci.
// Lanes = spatial: tq = lane>>4 (4 'to' per block), vo = lane&15 (13 valid).
template<int MODE, typename DT>
__global__ __launch_bounds__(256) void conv_k(const int* __restrict__ flag,
                                              const DT* __restrict__ x,
                                              const float* __restrict__ w32,
                                              const DT* __restrict__ bias,
                                              const DT* __restrict__ s_in,
                                              const float* __restrict__ a1,
                                              const float* __restrict__ b1,
                                              DT* __restrict__ y) {
    if (flag[0] != MODE) return;
    __shared__ __align__(16) float sh[CI_CHUNK][LROWS][28];
    const int tg   = blockIdx.x;        // 0..15 : group of 4 'to'
    const int cog  = blockIdx.y;        // 0..3  : group of 64 co
    const int n    = blockIdx.z;        // 0..63
    const int tid  = threadIdx.x;
    const int wid  = tid >> 6;
    const int lane = tid & 63;
    const int tq   = lane >> 4;         // 0..3
    const int vo   = lane & 15;         // 0..15 (13 valid)
    const int voc  = min(vo, 12);       // clamp -> idle lanes broadcast lane-12 addr
    const int co_w = __builtin_amdgcn_readfirstlane(cog * 64 + wid * 16);
    const int to   = tg * 4 + tq;
    const int tbase = 8 * tg - 1;       // t_in = tbase + lt, lt in [0,9)

    float acc[16];
#pragma unroll
    for (int j = 0; j < 16; j++) acc[j] = 0.f;

#pragma unroll 1
    for (int cc = 0; cc < CIN; cc += CI_CHUNK) {
        // ---- stage shift_in+BN1 chunk into LDS ----
        for (int e = tid; e < CI_CHUNK * LROWS * 27; e += 256) {
            int ci = e / (LROWS * 27);
            int r0 = e - ci * (LROWS * 27);
            int lt = r0 / 27;
            int vv = r0 - lt * 27;
            int t_in = tbase + lt;
            int v_in = vv - 1;
            float hv = 0.f;
            if (t_in >= 0 && t_in < T_ && v_in >= 0 && v_in < V_) {
                int gci = cc + ci;
                float s = ldv(&s_in[gci]);
                float tsrc = (float)t_in + s;
                float f0 = floorf(tsrc);
                float frac = tsrc - f0;
                int i0 = (int)f0;
                int i1 = i0 + 1;
                float w0 = (i0 >= 0 && i0 < T_) ? (1.f - frac) : 0.f;
                float w1 = (i1 >= 0 && i1 < T_) ? frac : 0.f;
                int i0c = min(max(i0, 0), T_ - 1);
                int i1c = min(max(i1, 0), T_ - 1);
                const DT* xc = x + ((size_t)n * CIN + gci) * (T_ * V_);
                float xv = w0 * ldv(&xc[i0c * V_ + v_in]) + w1 * ldv(&xc[i1c * V_ + v_in]);
                hv = a1[gci] * xv + b1[gci] * (w0 + w1);
            }
            sh[ci][lt][vv] = hv;
        }
        __syncthreads();

        // ---- inner product: lanes=spatial, wave=16 co, weights scalar ----
#pragma unroll 1
        for (int ci = 0; ci < CI_CHUNK; ci++) {
            // input taps: per kt one float pair-pair [2vo .. 2vo+3]
            float xv[3][3];
#pragma unroll
            for (int kt = 0; kt < 3; kt++) {
                const float2* rp = reinterpret_cast<const float2*>(&sh[ci][2 * tq + kt][2 * voc]);
                float2 p0 = rp[0];
                float2 p1 = rp[1];
                xv[kt][0] = p0.x; xv[kt][1] = p0.y; xv[kt][2] = p1.x;
            }
            const float* wrow = w32 + ((size_t)(cc + ci) * COUT + co_w) * 9;
#pragma unroll
            for (int j = 0; j < 16; j++) {
                const float* wj = wrow + j * 9;
                float a = acc[j];
                a += wj[0] * xv[0][0];
                a += wj[1] * xv[0][1];
                a += wj[2] * xv[0][2];
                a += wj[3] * xv[1][0];
                a += wj[4] * xv[1][1];
                a += wj[5] * xv[1][2];
                a += wj[6] * xv[2][0];
                a += wj[7] * xv[2][1];
                a += wj[8] * xv[2][2];
                acc[j] = a;
            }
        }
        __syncthreads();
    }

    // ---- epilogue: bias + relu + store (valid vo lanes only) ----
    if (vo < VOUT) {
#pragma unroll
        for (int j = 0; j < 16; j++) {
            int co = co_w + j;
            float bi = ldv(&bias[co]);
            DT* yp = y + (((size_t)n * COUT + co) * TOUT + to) * VOUT;
            stv(&yp[vo], fmaxf(acc[j] + bi, 0.f));
        }
    }
}

// ---- BN2 stats over z = shift_out(y): one block per output channel ----
template<int MODE, typename DT>
__global__ void bn2_k(const int* __restrict__ flag, const DT* __restrict__ y,
                      const DT* __restrict__ s_out,
                      const DT* __restrict__ gamma, const DT* __restrict__ beta,
                      float* __restrict__ a2, float* __restrict__ b2) {
    if (flag[0] != MODE) return;
    int co = blockIdx.x;
    float sv = ldv(&s_out[co]);
    float s = 0.f, ss = 0.f;
    for (int i = threadIdx.x; i < N_ * TOUT * VOUT; i += 256) {
        int n = i / (TOUT * VOUT);
        int r = i % (TOUT * VOUT);
        int to = r / VOUT;
        int vo = r % VOUT;
        float tsrc = (float)to + sv;
        float f0 = floorf(tsrc);
        float frac = tsrc - f0;
        int i0 = (int)f0, i1 = i0 + 1;
        float w0 = (i0 >= 0 && i0 < TOUT) ? (1.f - frac) : 0.f;
        float w1 = (i1 >= 0 && i1 < TOUT) ? frac : 0.f;
        int i0c = min(max(i0, 0), TOUT - 1);
        int i1c = min(max(i1, 0), TOUT - 1);
        const DT* yc = y + ((size_t)n * COUT + co) * (TOUT * VOUT);
        float z = w0 * ldv(&yc[i0c * VOUT + vo]) + w1 * ldv(&yc[i1c * VOUT + vo]);
        s += z; ss += z * z;
    }
    blockReduce2(s, ss);
    if (threadIdx.x == 0) {
        float cnt = (float)(N_ * TOUT * VOUT);
        float mean = s / cnt;
        float var = ss / cnt - mean * mean;
        float a = ldv(&gamma[co]) * rsqrtf(var + EPS_);
        a2[co] = a;
        b2[co] = ldv(&beta[co]) - mean * a;
    }
}

// ---- in-place: out = a2 * shift_out(y) + b2, per (n,co) plane via LDS ----
template<int MODE, typename DT>
__global__ void final_k(const int* __restrict__ flag, DT* __restrict__ y,
                        const DT* __restrict__ s_out,
                        const float* __restrict__ a2, const float* __restrict__ b2) {
    if (flag[0] != MODE) return;
    __shared__ float pl[TOUT * VOUT];
    int co = blockIdx.x, n = blockIdx.y;
    DT* base = y + ((size_t)n * COUT + co) * (TOUT * VOUT);
    for (int i = threadIdx.x; i < TOUT * VOUT; i += 256) pl[i] = ldv(&base[i]);
    __syncthreads();
    float sv = ldv(&s_out[co]);
    float A = a2[co], B = b2[co];
    for (int i = threadIdx.x; i < TOUT * VOUT; i += 256) {
        int to = i / VOUT, vo = i % VOUT;
        float tsrc = (float)to + sv;
        float f0 = floorf(tsrc);
        float frac = tsrc - f0;
        int i0 = (int)f0, i1 = i0 + 1;
        float w0 = (i0 >= 0 && i0 < TOUT) ? (1.f - frac) : 0.f;
        float w1 = (i1 >= 0 && i1 < TOUT) ? frac : 0.f;
        int i0c = min(max(i0, 0), TOUT - 1);
        int i1c = min(max(i1, 0), TOUT - 1);
        float z = w0 * pl[i0c * VOUT + vo] + w1 * pl[i1c * VOUT + vo];
        stv(&base[i], A * z + B);
    }
}

extern "C" void kernel_launch(void* const* d_in, const int* in_sizes, int n_in,
                              void* d_out, int out_size, void* d_ws, size_t ws_size,
                              hipStream_t stream) {
    // ws: flag (256B) | a1[128] | b1[128] | a2[256] | b2[256] | s1[128] | q1[128]
    //     | pad to 1KB | w32[256*128*9] (~1.18 MB fp32)
    int*   flag = (int*)d_ws;
    float* a1 = (float*)((char*)d_ws + 256);
    float* b1 = a1 + 128;
    float* a2 = b1 + 128;
    float* b2 = a2 + 256;
    float* s1 = b2 + 256;
    float* q1 = s1 + 128;
    float* w32 = (float*)((char*)d_ws + 8192);

    detect_k<<<1, 256, 0, stream>>>((const unsigned short*)d_in[0], flag, s1, q1);

    // MODE 0: bf16 tensors
    const bf16* xb    = (const bf16*)d_in[0];
    const bf16* g1b   = (const bf16*)d_in[1];
    const bf16* be1b  = (const bf16*)d_in[2];
    const bf16* sinb  = (const bf16*)d_in[3];
    const bf16* wbb   = (const bf16*)d_in[4];
    const bf16* cbb   = (const bf16*)d_in[5];
    const bf16* soutb = (const bf16*)d_in[6];
    const bf16* g2b   = (const bf16*)d_in[7];
    const bf16* be2b  = (const bf16*)d_in[8];
    bf16* yb = (bf16*)d_out;
    // MODE 1: fp32 tensors
    const float* xf    = (const float*)d_in[0];
    const float* g1f   = (const float*)d_in[1];
    const float* be1f  = (const float*)d_in[2];
    const float* sinf_ = (const float*)d_in[3];
    const float* wbf   = (const float*)d_in[4];
    const float* cbf   = (const float*)d_in[5];
    const float* soutf = (const float*)d_in[6];
    const float* g2f   = (const float*)d_in[7];
    const float* be2f  = (const float*)d_in[8];
    float* yf = (float*)d_out;

    wcvt_k<0, bf16> <<<dim3(256), 256, 0, stream>>>(flag, wbb, w32);
    wcvt_k<1, float><<<dim3(256), 256, 0, stream>>>(flag, wbf, w32);

    bn1_k<0, bf16> <<<dim3(CIN, 4), 256, 0, stream>>>(flag, xb, s1, q1);
    bn1_k<1, float><<<dim3(CIN, 4), 256, 0, stream>>>(flag, xf, s1, q1);
    bn1fin_k<0, bf16> <<<1, 128, 0, stream>>>(flag, g1b, be1b, s1, q1, a1, b1);
    bn1fin_k<1, float><<<1, 128, 0, stream>>>(flag, g1f, be1f, s1, q1, a1, b1);

    conv_k<0, bf16> <<<dim3(TOUT / 4, COUT / 64, N_), 256, 0, stream>>>(flag, xb, w32, cbb, sinb, a1, b1, yb);
    conv_k<1, float><<<dim3(TOUT / 4, COUT / 64, N_), 256, 0, stream>>>(flag, xf, w32, cbf, sinf_, a1, b1, yf);

    bn2_k<0, bf16> <<<dim3(COUT), 256, 0, stream>>>(flag, yb, soutb, g2b, be2b, a2, b2);
    bn2_k<1, float><<<dim3(COUT), 256, 0, stream>>>(flag, yf, soutf, g2f, be2f, a2, b2);

    final_k<0, bf16> <<<dim3(COUT, N_), 256, 0, stream>>>(flag, yb, soutb, a2, b2);
    final_k<1, float><<<dim3(COUT, N_), 256, 0, stream>>>(flag, yf, soutf, a2, b2);
}